// Round 8
// baseline (3643.391 us; speedup 1.0000x reference)
//
#include <hip/hip_runtime.h>
#include <hip/hip_bf16.h>
#include <math.h>

#define N0 50000
#define E0 1600000
#define K1 40000
#define K2 32000
#define FEAT 128
#define HID 128
#define EMB 64
#define NCLS 10

typedef __bf16 v8bf __attribute__((ext_vector_type(8)));
typedef __bf16 v4bf __attribute__((ext_vector_type(4)));
typedef float  v4f  __attribute__((ext_vector_type(4)));

static __device__ __forceinline__ unsigned f2key(float f) {
    unsigned u = __float_as_uint(f);
    return (u & 0x80000000u) ? ~u : (u | 0x80000000u);
}

// ---------- dtype detection ----------
__global__ void detect_dtype_kernel(const unsigned* __restrict__ w, int n, int* __restrict__ flag) {
    __shared__ int tot;
    if (threadIdx.x == 0) tot = 0;
    __syncthreads();
    int cnt = 0;
    for (int i = threadIdx.x; i < n; i += 256) {
        unsigned lo = w[i] & 0xFFFFu;
        unsigned e = (lo >> 7) & 0xFFu;
        cnt += (e >= 143);
    }
    atomicAdd(&tot, cnt);
    __syncthreads();
    if (threadIdx.x == 0) flag[0] = (tot > n / 8) ? 1 : 0;  // 1 = f32, 0 = bf16
}

static __device__ __forceinline__ float load_as_f32(const void* in, long long i, int isF32) {
    if (isF32) return ((const float*)in)[i];
    unsigned short h = ((const unsigned short*)in)[i];
    return __uint_as_float(((unsigned)h) << 16);
}

// x: one pass -> f32 + (hi,lo)
__global__ void x_convert_kernel(const void* __restrict__ in, float* __restrict__ xf,
                                 __bf16* __restrict__ hi, __bf16* __restrict__ lo, int n,
                                 const int* __restrict__ flag) {
    int i = blockIdx.x * 256 + threadIdx.x;
    if (i >= n) return;
    float v = load_as_f32(in, i, *flag);
    __bf16 h = (__bf16)v;
    xf[i] = v; hi[i] = h; lo[i] = (__bf16)(v - (float)h);
}

// batched weight splits (10 tensors in one launch)
struct SplitJob { const void* src; __bf16* hi; __bf16* lo; int n; };
struct SplitJobs { SplitJob j[10]; };
__global__ void split_all_kernel(SplitJobs jobs, const int* __restrict__ flag) {
    SplitJob jb = jobs.j[blockIdx.y];
    int i = blockIdx.x * 256 + threadIdx.x;
    if (i >= jb.n) return;
    float v = load_as_f32(jb.src, i, *flag);
    __bf16 h = (__bf16)v;
    jb.hi[i] = h; jb.lo[i] = (__bf16)(v - (float)h);
}

// batched small f32 conversions (9 tensors, one block each)
struct F32Job { const void* src; float* dst; int n; };
struct F32Jobs { F32Job j[9]; };
__global__ void f32_all_kernel(F32Jobs jobs, const int* __restrict__ flag) {
    F32Job jb = jobs.j[blockIdx.x];
    for (int i = threadIdx.x; i < jb.n; i += 256) jb.dst[i] = load_as_f32(jb.src, i, *flag);
}

// ---------- CSR build ----------
__global__ void deg_count_kernel(const int* __restrict__ src, const int* __restrict__ dst, int E,
                                 const int* __restrict__ m1, const int* __restrict__ m2,
                                 int* __restrict__ deg) {
    int e = blockIdx.x * 256 + threadIdx.x;
    if (e >= E) return;
    int s = src[e], d = dst[e];
    if (m1) { s = m1[s]; d = m1[d]; if (s < 0 || d < 0) return; }
    if (m2) { s = m2[s]; d = m2[d]; if (s < 0 || d < 0) return; }
    atomicAdd(&deg[d], 1);
}

__global__ void csr_fill_kernel(const int* __restrict__ src, const int* __restrict__ dst, int E,
                                const int* __restrict__ m1, const int* __restrict__ m2,
                                int* __restrict__ cursor, int* __restrict__ cols) {
    int e = blockIdx.x * 256 + threadIdx.x;
    if (e >= E) return;
    int s = src[e], d = dst[e];
    if (m1) { s = m1[s]; d = m1[d]; if (s < 0 || d < 0) return; }
    if (m2) { s = m2[s]; d = m2[d]; if (s < 0 || d < 0) return; }
    int p = atomicAdd(&cursor[d], 1);
    cols[p] = s;
}

// exclusive scan; also writes cursor (= rowptr copy for csr_fill)
__global__ void exclusive_scan_kernel(const int* __restrict__ deg, int* __restrict__ rowptr,
                                      int* __restrict__ cursor, int M) {
    __shared__ int part[1024];
    int t = threadIdx.x;
    int per = (M + 1023) / 1024;
    int s = 0;
    for (int k = 0; k < per; ++k) { int idx = t * per + k; if (idx < M) s += deg[idx]; }
    part[t] = s;
    __syncthreads();
    for (int off = 1; off < 1024; off <<= 1) {
        int v = 0;
        if (t >= off) v = part[t - off];
        __syncthreads();
        if (t >= off) part[t] += v;
        __syncthreads();
    }
    int run = (t > 0) ? part[t - 1] : 0;
    for (int k = 0; k < per; ++k) {
        int idx = t * per + k;
        if (idx < M) { rowptr[idx] = run; cursor[idx] = run; run += deg[idx]; }
    }
    if (t == 1023) rowptr[M] = part[1023];
}

// ---------- gather aggregation: f32 gather/accumulate, hi/lo bf16 out ----------
template<int C>
__global__ void aggregate_kernel(const int* __restrict__ rowptr, const int* __restrict__ cols,
                                 const float* __restrict__ x, __bf16* __restrict__ aggHi,
                                 __bf16* __restrict__ aggLo, int M) {
    const int CH = C / 4;
    const int NPB = 256 / CH;
    int n = blockIdx.x * NPB + threadIdx.x / CH;
    int c4 = threadIdx.x % CH;
    if (n >= M) return;
    int b = rowptr[n], e = rowptr[n + 1];
    float4 s = {0.f, 0.f, 0.f, 0.f};
    for (int j = b; j < e; ++j) {
        int src = cols[j];
        float4 v = ((const float4*)(x + (size_t)src * C))[c4];
        s.x += v.x; s.y += v.y; s.z += v.z; s.w += v.w;
    }
    v4bf h, l;
    h[0] = (__bf16)s.x; l[0] = (__bf16)(s.x - (float)h[0]);
    h[1] = (__bf16)s.y; l[1] = (__bf16)(s.y - (float)h[1]);
    h[2] = (__bf16)s.z; l[2] = (__bf16)(s.z - (float)h[2]);
    h[3] = (__bf16)s.w; l[3] = (__bf16)(s.w - (float)h[3]);
    *(v4bf*)(aggHi + (size_t)n * C + c4 * 4) = h;
    *(v4bf*)(aggLo + (size_t)n * C + c4 * 4) = l;
}

// ---------- split-precision MFMA dual linear + bias + relu ----------
template<int Cin, int Cout>
__global__ void linear_mfma_kernel(int M,
                                   const __bf16* __restrict__ Ahi, const __bf16* __restrict__ Alo,
                                   const __bf16* __restrict__ WaHi, const __bf16* __restrict__ WaLo,
                                   const __bf16* __restrict__ Bhi, const __bf16* __restrict__ Blo,
                                   const __bf16* __restrict__ WbHi, const __bf16* __restrict__ WbLo,
                                   const float* __restrict__ bias, float* __restrict__ outF) {
    constexpr int NG = Cout / 16;
    int wave = threadIdx.x >> 6;
    int lane = threadIdx.x & 63;
    int m = lane & 15, quad = lane >> 4;
    int row0 = blockIdx.x * 64 + wave * 16;
    int ra = row0 + m; if (ra > M - 1) ra = M - 1;

    v4f acc[NG];
#pragma unroll
    for (int g = 0; g < NG; ++g) acc[g] = (v4f){0.f, 0.f, 0.f, 0.f};

#pragma unroll
    for (int ks = 0; ks < Cin / 32; ++ks) {
        size_t aoff = (size_t)ra * Cin + ks * 32 + quad * 8;
        v8bf ah = *(const v8bf*)(Ahi + aoff);
        v8bf al = *(const v8bf*)(Alo + aoff);
#pragma unroll
        for (int g = 0; g < NG; ++g) {
            size_t woff = (size_t)(g * 16 + m) * Cin + ks * 32 + quad * 8;
            v8bf bh = *(const v8bf*)(WaHi + woff);
            v8bf bl = *(const v8bf*)(WaLo + woff);
            acc[g] = __builtin_amdgcn_mfma_f32_16x16x32_bf16(ah, bh, acc[g], 0, 0, 0);
            acc[g] = __builtin_amdgcn_mfma_f32_16x16x32_bf16(ah, bl, acc[g], 0, 0, 0);
            acc[g] = __builtin_amdgcn_mfma_f32_16x16x32_bf16(al, bh, acc[g], 0, 0, 0);
        }
    }
#pragma unroll
    for (int ks = 0; ks < Cin / 32; ++ks) {
        size_t aoff = (size_t)ra * Cin + ks * 32 + quad * 8;
        v8bf ah = *(const v8bf*)(Bhi + aoff);
        v8bf al = *(const v8bf*)(Blo + aoff);
#pragma unroll
        for (int g = 0; g < NG; ++g) {
            size_t woff = (size_t)(g * 16 + m) * Cin + ks * 32 + quad * 8;
            v8bf bh = *(const v8bf*)(WbHi + woff);
            v8bf bl = *(const v8bf*)(WbLo + woff);
            acc[g] = __builtin_amdgcn_mfma_f32_16x16x32_bf16(ah, bh, acc[g], 0, 0, 0);
            acc[g] = __builtin_amdgcn_mfma_f32_16x16x32_bf16(ah, bl, acc[g], 0, 0, 0);
            acc[g] = __builtin_amdgcn_mfma_f32_16x16x32_bf16(al, bh, acc[g], 0, 0, 0);
        }
    }

    // C/D layout: col = lane&15, row = quad*4 + reg
#pragma unroll
    for (int g = 0; g < NG; ++g) {
        int col = g * 16 + m;
        float bv = bias[col];
#pragma unroll
        for (int r = 0; r < 4; ++r) {
            int row = row0 + quad * 4 + r;
            if (row < M) outF[(size_t)row * Cout + col] = fmaxf(acc[g][r] + bv, 0.f);
        }
    }
}

// ---------- pooling score ----------
template<int C>
__global__ void score_kernel(const float* __restrict__ xin, const float* __restrict__ w,
                             int M, float* __restrict__ score) {
    int row = blockIdx.x * 4 + (threadIdx.x >> 6);
    int lane = threadIdx.x & 63;
    if (row >= M) return;
    float p = 0.f, q = 0.f;
#pragma unroll
    for (int c = lane; c < C; c += 64) {
        float wc = w[c];
        float xc = xin[(size_t)row * C + c];
        p += xc * wc; q += wc * wc;
    }
#pragma unroll
    for (int off = 32; off >= 1; off >>= 1) {
        p += __shfl_xor(p, off, 64);
        q += __shfl_xor(q, off, 64);
    }
    if (lane == 0) {
        float arg = p / sqrtf(q);
        score[row] = (float)tanh((double)arg);
    }
}

// ---------- single-block stable LSD radix argsort (4-bit x 8 passes) ----------
// ascending sort on key = ~f2key(score); stable => order = (score desc, index asc)
// == jax.lax.top_k order. Emits perm/mapping directly.
#define SORT_T 1024
__global__ __launch_bounds__(1024, 1)
void radix_argsort_pool_kernel(const float* __restrict__ score, int N, int K,
                               unsigned* __restrict__ keyA, int* __restrict__ idxA,
                               unsigned* __restrict__ keyB, int* __restrict__ idxB,
                               int* __restrict__ perm, int* __restrict__ mapping) {
    __shared__ unsigned bins[16 * SORT_T];   // per-(digit, thread) counts -> cursors
    __shared__ unsigned part[SORT_T];
    int t = threadIdx.x;
    for (int i = t; i < N; i += SORT_T) {
        keyA[i] = ~f2key(score[i]);
        idxA[i] = i;
    }
    __syncthreads();
    int chunk = (N + SORT_T - 1) / SORT_T;
    int e0 = t * chunk;
    int e1 = e0 + chunk; if (e1 > N) e1 = N;
    if (e0 > N) e0 = N;
    unsigned* srcK = keyA; int* srcI = idxA;
    unsigned* dstK = keyB; int* dstI = idxB;
    for (int shift = 0; shift < 32; shift += 4) {
#pragma unroll
        for (int d = 0; d < 16; ++d) bins[d * SORT_T + t] = 0;
        __syncthreads();
        for (int e = e0; e < e1; ++e) {
            unsigned d = (srcK[e] >> shift) & 15u;
            bins[d * SORT_T + t]++;
        }
        __syncthreads();
        // exclusive scan over flattened digit-major [16*SORT_T] array
        unsigned run = 0;
        int base = t * 16;
#pragma unroll
        for (int k = 0; k < 16; ++k) {
            unsigned v = bins[base + k];
            bins[base + k] = run;
            run += v;
        }
        part[t] = run;
        __syncthreads();
        for (int o = 1; o < SORT_T; o <<= 1) {
            unsigned v = (t >= o) ? part[t - o] : 0u;
            __syncthreads();
            part[t] += v;
            __syncthreads();
        }
        unsigned add = (t > 0) ? part[t - 1] : 0u;
#pragma unroll
        for (int k = 0; k < 16; ++k) bins[base + k] += add;
        __syncthreads();
        // stable scatter (per-thread contiguous chunk preserves order)
        for (int e = e0; e < e1; ++e) {
            unsigned key = srcK[e];
            unsigned d = (key >> shift) & 15u;
            unsigned pos = bins[d * SORT_T + t]++;
            dstK[pos] = key;
            dstI[pos] = srcI[e];
        }
        __syncthreads();
        unsigned* tk = srcK; srcK = dstK; dstK = tk;
        int* ti = srcI; srcI = dstI; dstI = ti;
    }
    for (int r = t; r < N; r += SORT_T) {
        int i = srcI[r];
        if (r < K) { perm[r] = i; mapping[i] = r; }
        else mapping[i] = -1;
    }
}

// xp[j] = x[perm[j]] * score[perm[j]]  -> f32 + (hi,lo)
template<int C>
__global__ void pool_apply_kernel(const float* __restrict__ xin, const float* __restrict__ score,
                                  const int* __restrict__ perm, float* __restrict__ xpF,
                                  __bf16* __restrict__ xpHi, __bf16* __restrict__ xpLo, int K) {
    const int CH = C / 4;
    int tid = blockIdx.x * 256 + threadIdx.x;
    int j = tid / CH, c4 = tid % CH;
    if (j >= K) return;
    int src = perm[j];
    float s = score[src];
    float4 v = ((const float4*)(xin + (size_t)src * C))[c4];
    v.x *= s; v.y *= s; v.z *= s; v.w *= s;
    ((float4*)(xpF + (size_t)j * C))[c4] = v;
    v4bf h, l;
    h[0] = (__bf16)v.x; l[0] = (__bf16)(v.x - (float)h[0]);
    h[1] = (__bf16)v.y; l[1] = (__bf16)(v.y - (float)h[1]);
    h[2] = (__bf16)v.z; l[2] = (__bf16)(v.z - (float)h[2]);
    h[3] = (__bf16)v.w; l[3] = (__bf16)(v.w - (float)h[3]);
    *(v4bf*)(xpHi + (size_t)j * C + c4 * 4) = h;
    *(v4bf*)(xpLo + (size_t)j * C + c4 * 4) = l;
}

// u[j] = base[j] + (mapping[j]>=0 ? deep[mapping[j]] : 0)  -> f32 + (hi,lo); uF may alias base
template<int C>
__global__ void unpool_add_kernel(const float* __restrict__ base, const float* __restrict__ deep,
                                  const int* __restrict__ mapping, float* __restrict__ uF,
                                  __bf16* __restrict__ uHi, __bf16* __restrict__ uLo, int M) {
    const int CH = C / 4;
    int tid = blockIdx.x * 256 + threadIdx.x;
    int j = tid / CH, c4 = tid % CH;
    if (j >= M) return;
    float4 v = ((const float4*)(base + (size_t)j * C))[c4];
    int m = mapping[j];
    if (m >= 0) {
        float4 d = ((const float4*)(deep + (size_t)m * C))[c4];
        v.x += d.x; v.y += d.y; v.z += d.z; v.w += d.w;
    }
    ((float4*)(uF + (size_t)j * C))[c4] = v;
    v4bf h, l;
    h[0] = (__bf16)v.x; l[0] = (__bf16)(v.x - (float)h[0]);
    h[1] = (__bf16)v.y; l[1] = (__bf16)(v.y - (float)h[1]);
    h[2] = (__bf16)v.z; l[2] = (__bf16)(v.z - (float)h[2]);
    h[3] = (__bf16)v.w; l[3] = (__bf16)(v.w - (float)h[3]);
    *(v4bf*)(uHi + (size_t)j * C + c4 * 4) = h;
    *(v4bf*)(uLo + (size_t)j * C + c4 * 4) = l;
}

__global__ void head_kernel(const float* __restrict__ x5, const float* __restrict__ lw,
                            const float* __restrict__ lb, void* __restrict__ out, int M,
                            const int* __restrict__ flag) {
    int row = blockIdx.x * 4 + (threadIdx.x >> 6);
    int lane = threadIdx.x & 63;
    if (row >= M) return;
    float a0 = x5[(size_t)row * 128 + lane];
    float a1 = x5[(size_t)row * 128 + 64 + lane];
    float d[NCLS];
#pragma unroll
    for (int o = 0; o < NCLS; ++o) {
        float p = a0 * lw[o * 128 + lane] + a1 * lw[o * 128 + 64 + lane];
#pragma unroll
        for (int off = 32; off >= 1; off >>= 1) p += __shfl_xor(p, off, 64);
        d[o] = p + lb[o];
    }
    float mx = d[0];
#pragma unroll
    for (int o = 1; o < NCLS; ++o) mx = fmaxf(mx, d[o]);
    float s = 0.f;
#pragma unroll
    for (int o = 0; o < NCLS; ++o) s += expf(d[o] - mx);
    float lse = mx + logf(s);
    if (lane < NCLS) {
        float v = d[0];
#pragma unroll
        for (int o = 1; o < NCLS; ++o) if (lane == o) v = d[o];
        float r = v - lse;
        if (*flag) ((float*)out)[(size_t)row * NCLS + lane] = r;
        else ((__hip_bfloat16*)out)[(size_t)row * NCLS + lane] = __float2bfloat16(r);
    }
}

extern "C" void kernel_launch(void* const* d_in, const int* in_sizes, int n_in,
                              void* d_out, int out_size, void* d_ws, size_t ws_size,
                              hipStream_t stream) {
    const void* x_raw   = d_in[0];
    const int*  ei      = (const int*)d_in[1];
    const void* w1_rel  = d_in[2];
    const void* w1_root = d_in[3];
    const void* b1      = d_in[4];
    const void* p1w     = d_in[5];
    const void* w2_rel  = d_in[6];
    const void* w2_root = d_in[7];
    const void* b2      = d_in[8];
    const void* p2w     = d_in[9];
    const void* w3_rel  = d_in[10];
    const void* w3_root = d_in[11];
    const void* b3      = d_in[12];
    const void* w4_rel  = d_in[13];
    const void* w4_root = d_in[14];
    const void* b4      = d_in[15];
    const void* w5_rel  = d_in[16];
    const void* w5_root = d_in[17];
    const void* b5      = d_in[18];
    const void* lw      = d_in[19];
    const void* lb      = d_in[20];

    char* base = (char*)d_ws;
    size_t off = 0;
    auto alloc = [&](size_t bytes) -> void* {
        void* p = base + off;
        off = (off + bytes + 255) & ~(size_t)255;
        return p;
    };
    int* flag = (int*)alloc(256);
    __bf16* w1rHi = (__bf16*)alloc(HID * FEAT * 2); __bf16* w1rLo = (__bf16*)alloc(HID * FEAT * 2);
    __bf16* w1tHi = (__bf16*)alloc(HID * FEAT * 2); __bf16* w1tLo = (__bf16*)alloc(HID * FEAT * 2);
    __bf16* w2rHi = (__bf16*)alloc(EMB * HID * 2);  __bf16* w2rLo = (__bf16*)alloc(EMB * HID * 2);
    __bf16* w2tHi = (__bf16*)alloc(EMB * HID * 2);  __bf16* w2tLo = (__bf16*)alloc(EMB * HID * 2);
    __bf16* w3rHi = (__bf16*)alloc(EMB * EMB * 2);  __bf16* w3rLo = (__bf16*)alloc(EMB * EMB * 2);
    __bf16* w3tHi = (__bf16*)alloc(EMB * EMB * 2);  __bf16* w3tLo = (__bf16*)alloc(EMB * EMB * 2);
    __bf16* w4rHi = (__bf16*)alloc(HID * EMB * 2);  __bf16* w4rLo = (__bf16*)alloc(HID * EMB * 2);
    __bf16* w4tHi = (__bf16*)alloc(HID * EMB * 2);  __bf16* w4tLo = (__bf16*)alloc(HID * EMB * 2);
    __bf16* w5rHi = (__bf16*)alloc(FEAT * HID * 2); __bf16* w5rLo = (__bf16*)alloc(FEAT * HID * 2);
    __bf16* w5tHi = (__bf16*)alloc(FEAT * HID * 2); __bf16* w5tLo = (__bf16*)alloc(FEAT * HID * 2);
    float* b1f = (float*)alloc(HID * 4);
    float* b2f = (float*)alloc(EMB * 4);
    float* b3f = (float*)alloc(EMB * 4);
    float* b4f = (float*)alloc(HID * 4);
    float* b5f = (float*)alloc(FEAT * 4);
    float* p1f = (float*)alloc(HID * 4);
    float* p2f = (float*)alloc(EMB * 4);
    float* lwf = (float*)alloc(NCLS * FEAT * 4);
    float* lbf = (float*)alloc(NCLS * 4);
    float* score = (float*)alloc((size_t)N0 * 4);
    unsigned* keyA = (unsigned*)alloc((size_t)N0 * 4);
    int*      idxA = (int*)alloc((size_t)N0 * 4);
    unsigned* keyB = (unsigned*)alloc((size_t)N0 * 4);
    int*      idxB = (int*)alloc((size_t)N0 * 4);
    int* perm1 = (int*)alloc((size_t)K1 * 4);
    int* map1  = (int*)alloc((size_t)N0 * 4);
    int* perm2 = (int*)alloc((size_t)K2 * 4);
    int* map2  = (int*)alloc((size_t)K1 * 4);
    int* deg   = (int*)alloc((size_t)(N0 + 1) * 4);
    int* cursor= (int*)alloc((size_t)(N0 + 1) * 4);
    int* rp0   = (int*)alloc((size_t)(N0 + 1) * 4);
    int* rp1   = (int*)alloc((size_t)(K1 + 1) * 4);
    int* rp2   = (int*)alloc((size_t)(K2 + 1) * 4);
    int* cols0 = (int*)alloc((size_t)E0 * 4);
    int* cols1 = (int*)alloc((size_t)E0 * 4);
    int* cols2 = (int*)alloc((size_t)E0 * 4);
    // aliased activation arenas
    char*   arenaX  = (char*)alloc((size_t)N0 * 128 * 4);   // xf -> xp1f -> {xp2f,x3f} -> x4f -> x5f
    __bf16* arenaHi = (__bf16*)alloc((size_t)N0 * 128 * 2);
    __bf16* arenaLo = (__bf16*)alloc((size_t)N0 * 128 * 2);
    __bf16* aggHi   = (__bf16*)alloc((size_t)N0 * 128 * 2);
    __bf16* aggLo   = (__bf16*)alloc((size_t)N0 * 128 * 2);
    float*  x1f     = (float*)alloc((size_t)N0 * 128 * 4);  // persists; becomes u2 f32 in-place
    float*  x2f     = (float*)alloc((size_t)K1 * 64 * 4);   // persists; becomes u1 f32 in-place

    float* xf   = (float*)arenaX;
    float* xp1f = (float*)arenaX;
    float* xp2f = (float*)arenaX;
    float* x3f  = (float*)(arenaX + 8388608);
    float* x4f  = (float*)arenaX;
    float* x5f  = (float*)arenaX;
    __bf16 *xHi = arenaHi,  *xLo = arenaLo;
    __bf16 *xp1Hi = arenaHi, *xp1Lo = arenaLo;
    __bf16 *xp2Hi = arenaHi, *xp2Lo = arenaLo;
    __bf16 *u1Hi = arenaHi,  *u1Lo = arenaLo;
    __bf16 *u2Hi = arenaHi,  *u2Lo = arenaLo;
    float* u1f = x2f;

    const int* src0 = ei;
    const int* dst0 = ei + E0;

    auto g = [](long long n, int b) -> unsigned { return (unsigned)((n + b - 1) / b); };

    // ---- dtype detect + fused conversions ----
    detect_dtype_kernel<<<1, 256, 0, stream>>>((const unsigned*)x_raw, 4096, flag);
    x_convert_kernel<<<g((long long)N0 * FEAT, 256), 256, 0, stream>>>(x_raw, xf, xHi, xLo, N0 * FEAT, flag);
    {
        SplitJobs sj;
        sj.j[0] = {w1_rel,  w1rHi, w1rLo, HID * FEAT};
        sj.j[1] = {w1_root, w1tHi, w1tLo, HID * FEAT};
        sj.j[2] = {w2_rel,  w2rHi, w2rLo, EMB * HID};
        sj.j[3] = {w2_root, w2tHi, w2tLo, EMB * HID};
        sj.j[4] = {w3_rel,  w3rHi, w3rLo, EMB * EMB};
        sj.j[5] = {w3_root, w3tHi, w3tLo, EMB * EMB};
        sj.j[6] = {w4_rel,  w4rHi, w4rLo, HID * EMB};
        sj.j[7] = {w4_root, w4tHi, w4tLo, HID * EMB};
        sj.j[8] = {w5_rel,  w5rHi, w5rLo, FEAT * HID};
        sj.j[9] = {w5_root, w5tHi, w5tLo, FEAT * HID};
        dim3 grid(g(HID * FEAT, 256), 10);
        split_all_kernel<<<grid, 256, 0, stream>>>(sj, flag);
    }
    {
        F32Jobs fj;
        fj.j[0] = {b1, b1f, HID};
        fj.j[1] = {b2, b2f, EMB};
        fj.j[2] = {b3, b3f, EMB};
        fj.j[3] = {b4, b4f, HID};
        fj.j[4] = {b5, b5f, FEAT};
        fj.j[5] = {p1w, p1f, HID};
        fj.j[6] = {p2w, p2f, EMB};
        fj.j[7] = {lw, lwf, NCLS * FEAT};
        fj.j[8] = {lb, lbf, NCLS};
        f32_all_kernel<<<9, 256, 0, stream>>>(fj, flag);
    }

    // ---- CSR graph0 ----
    hipMemsetAsync(deg, 0, (size_t)N0 * 4, stream);
    deg_count_kernel<<<g(E0, 256), 256, 0, stream>>>(src0, dst0, E0, nullptr, nullptr, deg);
    exclusive_scan_kernel<<<1, 1024, 0, stream>>>(deg, rp0, cursor, N0);
    csr_fill_kernel<<<g(E0, 256), 256, 0, stream>>>(src0, dst0, E0, nullptr, nullptr, cursor, cols0);

    // ---- Layer 1 ----
    aggregate_kernel<128><<<g(N0, 8), 256, 0, stream>>>(rp0, cols0, xf, aggHi, aggLo, N0);
    linear_mfma_kernel<128, 128><<<g(N0, 64), 256, 0, stream>>>(N0, aggHi, aggLo, w1rHi, w1rLo,
                                                                xHi, xLo, w1tHi, w1tLo, b1f, x1f);

    // ---- Pool 1 ----
    score_kernel<128><<<g(N0, 4), 256, 0, stream>>>(x1f, p1f, N0, score);
    radix_argsort_pool_kernel<<<1, 1024, 0, stream>>>(score, N0, K1, keyA, idxA, keyB, idxB, perm1, map1);
    pool_apply_kernel<128><<<g((long long)K1 * 32, 256), 256, 0, stream>>>(x1f, score, perm1, xp1f, xp1Hi, xp1Lo, K1);

    // ---- CSR graph1 ----
    hipMemsetAsync(deg, 0, (size_t)K1 * 4, stream);
    deg_count_kernel<<<g(E0, 256), 256, 0, stream>>>(src0, dst0, E0, map1, nullptr, deg);
    exclusive_scan_kernel<<<1, 1024, 0, stream>>>(deg, rp1, cursor, K1);
    csr_fill_kernel<<<g(E0, 256), 256, 0, stream>>>(src0, dst0, E0, map1, nullptr, cursor, cols1);

    // ---- Layer 2 ----
    aggregate_kernel<128><<<g(K1, 8), 256, 0, stream>>>(rp1, cols1, xp1f, aggHi, aggLo, K1);
    linear_mfma_kernel<128, 64><<<g(K1, 64), 256, 0, stream>>>(K1, aggHi, aggLo, w2rHi, w2rLo,
                                                               xp1Hi, xp1Lo, w2tHi, w2tLo, b2f, x2f);

    // ---- Pool 2 ----
    score_kernel<64><<<g(K1, 4), 256, 0, stream>>>(x2f, p2f, K1, score);
    radix_argsort_pool_kernel<<<1, 1024, 0, stream>>>(score, K1, K2, keyA, idxA, keyB, idxB, perm2, map2);
    pool_apply_kernel<64><<<g((long long)K2 * 16, 256), 256, 0, stream>>>(x2f, score, perm2, xp2f, xp2Hi, xp2Lo, K2);

    // ---- CSR graph2 ----
    hipMemsetAsync(deg, 0, (size_t)K2 * 4, stream);
    deg_count_kernel<<<g(E0, 256), 256, 0, stream>>>(src0, dst0, E0, map1, map2, deg);
    exclusive_scan_kernel<<<1, 1024, 0, stream>>>(deg, rp2, cursor, K2);
    csr_fill_kernel<<<g(E0, 256), 256, 0, stream>>>(src0, dst0, E0, map1, map2, cursor, cols2);

    // ---- Layer 3 ----
    aggregate_kernel<64><<<g(K2, 16), 256, 0, stream>>>(rp2, cols2, xp2f, aggHi, aggLo, K2);
    linear_mfma_kernel<64, 64><<<g(K2, 64), 256, 0, stream>>>(K2, aggHi, aggLo, w3rHi, w3rLo,
                                                              xp2Hi, xp2Lo, w3tHi, w3tLo, b3f, x3f);

    // ---- Unpool 1 (in-place on x2f) ----
    unpool_add_kernel<64><<<g((long long)K1 * 16, 256), 256, 0, stream>>>(x2f, x3f, map2, u1f, u1Hi, u1Lo, K1);

    // ---- Layer 4 ----
    aggregate_kernel<64><<<g(K1, 16), 256, 0, stream>>>(rp1, cols1, u1f, aggHi, aggLo, K1);
    linear_mfma_kernel<64, 128><<<g(K1, 64), 256, 0, stream>>>(K1, aggHi, aggLo, w4rHi, w4rLo,
                                                               u1Hi, u1Lo, w4tHi, w4tLo, b4f, x4f);

    // ---- Unpool 2 (f32 in-place on x1f) ----
    unpool_add_kernel<128><<<g((long long)N0 * 32, 256), 256, 0, stream>>>(x1f, x4f, map1, x1f, u2Hi, u2Lo, N0);

    // ---- Layer 5 ----
    aggregate_kernel<128><<<g(N0, 8), 256, 0, stream>>>(rp0, cols0, x1f, aggHi, aggLo, N0);
    linear_mfma_kernel<128, 128><<<g(N0, 64), 256, 0, stream>>>(N0, aggHi, aggLo, w5rHi, w5rLo,
                                                                u2Hi, u2Lo, w5tHi, w5tLo, b5f, x5f);

    // ---- Head ----
    head_kernel<<<g(N0, 4), 256, 0, stream>>>(x5f, lwf, lbf, d_out, N0, flag);
}

// Round 9
// 1761.745 us; speedup vs baseline: 2.0681x; 2.0681x over previous
//
#include <hip/hip_runtime.h>
#include <hip/hip_bf16.h>
#include <math.h>

#define N0 50000
#define E0 1600000
#define K1 40000
#define K2 32000
#define FEAT 128
#define HID 128
#define EMB 64
#define NCLS 10

typedef __bf16 v8bf __attribute__((ext_vector_type(8)));
typedef __bf16 v4bf __attribute__((ext_vector_type(4)));
typedef float  v4f  __attribute__((ext_vector_type(4)));

static __device__ __forceinline__ unsigned f2key(float f) {
    unsigned u = __float_as_uint(f);
    return (u & 0x80000000u) ? ~u : (u | 0x80000000u);
}

// ---------- dtype detection ----------
__global__ void detect_dtype_kernel(const unsigned* __restrict__ w, int n, int* __restrict__ flag) {
    __shared__ int tot;
    if (threadIdx.x == 0) tot = 0;
    __syncthreads();
    int cnt = 0;
    for (int i = threadIdx.x; i < n; i += 256) {
        unsigned lo = w[i] & 0xFFFFu;
        unsigned e = (lo >> 7) & 0xFFu;
        cnt += (e >= 143);
    }
    atomicAdd(&tot, cnt);
    __syncthreads();
    if (threadIdx.x == 0) flag[0] = (tot > n / 8) ? 1 : 0;  // 1 = f32, 0 = bf16
}

static __device__ __forceinline__ float load_as_f32(const void* in, long long i, int isF32) {
    if (isF32) return ((const float*)in)[i];
    unsigned short h = ((const unsigned short*)in)[i];
    return __uint_as_float(((unsigned)h) << 16);
}

// x: one pass -> f32 + (hi,lo)
__global__ void x_convert_kernel(const void* __restrict__ in, float* __restrict__ xf,
                                 __bf16* __restrict__ hi, __bf16* __restrict__ lo, int n,
                                 const int* __restrict__ flag) {
    int i = blockIdx.x * 256 + threadIdx.x;
    if (i >= n) return;
    float v = load_as_f32(in, i, *flag);
    __bf16 h = (__bf16)v;
    xf[i] = v; hi[i] = h; lo[i] = (__bf16)(v - (float)h);
}

// batched weight splits (10 tensors in one launch)
struct SplitJob { const void* src; __bf16* hi; __bf16* lo; int n; };
struct SplitJobs { SplitJob j[10]; };
__global__ void split_all_kernel(SplitJobs jobs, const int* __restrict__ flag) {
    SplitJob jb = jobs.j[blockIdx.y];
    int i = blockIdx.x * 256 + threadIdx.x;
    if (i >= jb.n) return;
    float v = load_as_f32(jb.src, i, *flag);
    __bf16 h = (__bf16)v;
    jb.hi[i] = h; jb.lo[i] = (__bf16)(v - (float)h);
}

// batched small f32 conversions (9 tensors, one block each)
struct F32Job { const void* src; float* dst; int n; };
struct F32Jobs { F32Job j[9]; };
__global__ void f32_all_kernel(F32Jobs jobs, const int* __restrict__ flag) {
    F32Job jb = jobs.j[blockIdx.x];
    for (int i = threadIdx.x; i < jb.n; i += 256) jb.dst[i] = load_as_f32(jb.src, i, *flag);
}

// ---------- CSR build ----------
__global__ void deg_count_kernel(const int* __restrict__ src, const int* __restrict__ dst, int E,
                                 const int* __restrict__ m1, const int* __restrict__ m2,
                                 int* __restrict__ deg) {
    int e = blockIdx.x * 256 + threadIdx.x;
    if (e >= E) return;
    int s = src[e], d = dst[e];
    if (m1) { s = m1[s]; d = m1[d]; if (s < 0 || d < 0) return; }
    if (m2) { s = m2[s]; d = m2[d]; if (s < 0 || d < 0) return; }
    atomicAdd(&deg[d], 1);
}

__global__ void csr_fill_kernel(const int* __restrict__ src, const int* __restrict__ dst, int E,
                                const int* __restrict__ m1, const int* __restrict__ m2,
                                int* __restrict__ cursor, int* __restrict__ cols) {
    int e = blockIdx.x * 256 + threadIdx.x;
    if (e >= E) return;
    int s = src[e], d = dst[e];
    if (m1) { s = m1[s]; d = m1[d]; if (s < 0 || d < 0) return; }
    if (m2) { s = m2[s]; d = m2[d]; if (s < 0 || d < 0) return; }
    int p = atomicAdd(&cursor[d], 1);
    cols[p] = s;
}

// exclusive scan; also writes cursor (= rowptr copy for csr_fill)
__global__ void exclusive_scan_kernel(const int* __restrict__ deg, int* __restrict__ rowptr,
                                      int* __restrict__ cursor, int M) {
    __shared__ int part[1024];
    int t = threadIdx.x;
    int per = (M + 1023) / 1024;
    int s = 0;
    for (int k = 0; k < per; ++k) { int idx = t * per + k; if (idx < M) s += deg[idx]; }
    part[t] = s;
    __syncthreads();
    for (int off = 1; off < 1024; off <<= 1) {
        int v = 0;
        if (t >= off) v = part[t - off];
        __syncthreads();
        if (t >= off) part[t] += v;
        __syncthreads();
    }
    int run = (t > 0) ? part[t - 1] : 0;
    for (int k = 0; k < per; ++k) {
        int idx = t * per + k;
        if (idx < M) { rowptr[idx] = run; cursor[idx] = run; run += deg[idx]; }
    }
    if (t == 1023) rowptr[M] = part[1023];
}

// ---------- gather aggregation: f32 gather/accumulate, hi/lo bf16 out ----------
template<int C>
__global__ void aggregate_kernel(const int* __restrict__ rowptr, const int* __restrict__ cols,
                                 const float* __restrict__ x, __bf16* __restrict__ aggHi,
                                 __bf16* __restrict__ aggLo, int M) {
    const int CH = C / 4;
    const int NPB = 256 / CH;
    int n = blockIdx.x * NPB + threadIdx.x / CH;
    int c4 = threadIdx.x % CH;
    if (n >= M) return;
    int b = rowptr[n], e = rowptr[n + 1];
    float4 s = {0.f, 0.f, 0.f, 0.f};
    for (int j = b; j < e; ++j) {
        int src = cols[j];
        float4 v = ((const float4*)(x + (size_t)src * C))[c4];
        s.x += v.x; s.y += v.y; s.z += v.z; s.w += v.w;
    }
    v4bf h, l;
    h[0] = (__bf16)s.x; l[0] = (__bf16)(s.x - (float)h[0]);
    h[1] = (__bf16)s.y; l[1] = (__bf16)(s.y - (float)h[1]);
    h[2] = (__bf16)s.z; l[2] = (__bf16)(s.z - (float)h[2]);
    h[3] = (__bf16)s.w; l[3] = (__bf16)(s.w - (float)h[3]);
    *(v4bf*)(aggHi + (size_t)n * C + c4 * 4) = h;
    *(v4bf*)(aggLo + (size_t)n * C + c4 * 4) = l;
}

// ---------- split-precision MFMA dual linear + bias + relu ----------
template<int Cin, int Cout>
__global__ void linear_mfma_kernel(int M,
                                   const __bf16* __restrict__ Ahi, const __bf16* __restrict__ Alo,
                                   const __bf16* __restrict__ WaHi, const __bf16* __restrict__ WaLo,
                                   const __bf16* __restrict__ Bhi, const __bf16* __restrict__ Blo,
                                   const __bf16* __restrict__ WbHi, const __bf16* __restrict__ WbLo,
                                   const float* __restrict__ bias, float* __restrict__ outF) {
    constexpr int NG = Cout / 16;
    int wave = threadIdx.x >> 6;
    int lane = threadIdx.x & 63;
    int m = lane & 15, quad = lane >> 4;
    int row0 = blockIdx.x * 64 + wave * 16;
    int ra = row0 + m; if (ra > M - 1) ra = M - 1;

    v4f acc[NG];
#pragma unroll
    for (int g = 0; g < NG; ++g) acc[g] = (v4f){0.f, 0.f, 0.f, 0.f};

#pragma unroll
    for (int ks = 0; ks < Cin / 32; ++ks) {
        size_t aoff = (size_t)ra * Cin + ks * 32 + quad * 8;
        v8bf ah = *(const v8bf*)(Ahi + aoff);
        v8bf al = *(const v8bf*)(Alo + aoff);
#pragma unroll
        for (int g = 0; g < NG; ++g) {
            size_t woff = (size_t)(g * 16 + m) * Cin + ks * 32 + quad * 8;
            v8bf bh = *(const v8bf*)(WaHi + woff);
            v8bf bl = *(const v8bf*)(WaLo + woff);
            acc[g] = __builtin_amdgcn_mfma_f32_16x16x32_bf16(ah, bh, acc[g], 0, 0, 0);
            acc[g] = __builtin_amdgcn_mfma_f32_16x16x32_bf16(ah, bl, acc[g], 0, 0, 0);
            acc[g] = __builtin_amdgcn_mfma_f32_16x16x32_bf16(al, bh, acc[g], 0, 0, 0);
        }
    }
#pragma unroll
    for (int ks = 0; ks < Cin / 32; ++ks) {
        size_t aoff = (size_t)ra * Cin + ks * 32 + quad * 8;
        v8bf ah = *(const v8bf*)(Bhi + aoff);
        v8bf al = *(const v8bf*)(Blo + aoff);
#pragma unroll
        for (int g = 0; g < NG; ++g) {
            size_t woff = (size_t)(g * 16 + m) * Cin + ks * 32 + quad * 8;
            v8bf bh = *(const v8bf*)(WbHi + woff);
            v8bf bl = *(const v8bf*)(WbLo + woff);
            acc[g] = __builtin_amdgcn_mfma_f32_16x16x32_bf16(ah, bh, acc[g], 0, 0, 0);
            acc[g] = __builtin_amdgcn_mfma_f32_16x16x32_bf16(ah, bl, acc[g], 0, 0, 0);
            acc[g] = __builtin_amdgcn_mfma_f32_16x16x32_bf16(al, bh, acc[g], 0, 0, 0);
        }
    }

    // C/D layout: col = lane&15, row = quad*4 + reg
#pragma unroll
    for (int g = 0; g < NG; ++g) {
        int col = g * 16 + m;
        float bv = bias[col];
#pragma unroll
        for (int r = 0; r < 4; ++r) {
            int row = row0 + quad * 4 + r;
            if (row < M) outF[(size_t)row * Cout + col] = fmaxf(acc[g][r] + bv, 0.f);
        }
    }
}

// ---------- pooling score ----------
template<int C>
__global__ void score_kernel(const float* __restrict__ xin, const float* __restrict__ w,
                             int M, float* __restrict__ score) {
    int row = blockIdx.x * 4 + (threadIdx.x >> 6);
    int lane = threadIdx.x & 63;
    if (row >= M) return;
    float p = 0.f, q = 0.f;
#pragma unroll
    for (int c = lane; c < C; c += 64) {
        float wc = w[c];
        float xc = xin[(size_t)row * C + c];
        p += xc * wc; q += wc * wc;
    }
#pragma unroll
    for (int off = 32; off >= 1; off >>= 1) {
        p += __shfl_xor(p, off, 64);
        q += __shfl_xor(q, off, 64);
    }
    if (lane == 0) {
        float arg = p / sqrtf(q);
        score[row] = (float)tanh((double)arg);
    }
}

__global__ void build_keys_kernel(const float* __restrict__ score, unsigned long long* __restrict__ keys, int N) {
    int i = blockIdx.x * 256 + threadIdx.x;
    if (i < N) keys[i] = ((unsigned long long)f2key(score[i]) << 32) | (unsigned)(~i);
}

// rank(i) = #{j : ckey_j > ckey_i}; 2 keys/thread, RT=2048 (16KB LDS -> high occupancy)
#define RT 2048
__global__ void rank_count_kernel(const unsigned long long* __restrict__ keys, int N, int* __restrict__ rank) {
    __shared__ unsigned long long sk[RT];
    int j0 = blockIdx.y * RT;
    int tile = N - j0; if (tile > RT) tile = RT;
    for (int t = threadIdx.x; t < tile; t += 256) sk[t] = keys[j0 + t];
    __syncthreads();
    int i0 = blockIdx.x * 512 + threadIdx.x;
    int i1 = i0 + 256;
    unsigned long long c0 = (i0 < N) ? keys[i0] : ~0ull;
    unsigned long long c1 = (i1 < N) ? keys[i1] : ~0ull;
    int n0 = 0, n1 = 0;
    int t = 0;
    for (; t + 8 <= tile; t += 8) {
        unsigned long long a = sk[t], b = sk[t+1], c = sk[t+2], d = sk[t+3];
        unsigned long long e = sk[t+4], f = sk[t+5], g = sk[t+6], h = sk[t+7];
        n0 += (a > c0); n0 += (b > c0); n0 += (c > c0); n0 += (d > c0);
        n0 += (e > c0); n0 += (f > c0); n0 += (g > c0); n0 += (h > c0);
        n1 += (a > c1); n1 += (b > c1); n1 += (c > c1); n1 += (d > c1);
        n1 += (e > c1); n1 += (f > c1); n1 += (g > c1); n1 += (h > c1);
    }
    for (; t < tile; ++t) {
        unsigned long long a = sk[t];
        n0 += (a > c0); n1 += (a > c1);
    }
    if (i0 < N && n0) atomicAdd(&rank[i0], n0);
    if (i1 < N && n1) atomicAdd(&rank[i1], n1);
}

__global__ void finalize_perm_kernel(const int* __restrict__ rank, int N, int K,
                                     int* __restrict__ perm, int* __restrict__ mapping) {
    int i = blockIdx.x * 256 + threadIdx.x;
    if (i >= N) return;
    int r = rank[i];
    if (r < K) { perm[r] = i; mapping[i] = r; }
    else mapping[i] = -1;
}

// xp[j] = x[perm[j]] * score[perm[j]]  -> f32 + (hi,lo)
template<int C>
__global__ void pool_apply_kernel(const float* __restrict__ xin, const float* __restrict__ score,
                                  const int* __restrict__ perm, float* __restrict__ xpF,
                                  __bf16* __restrict__ xpHi, __bf16* __restrict__ xpLo, int K) {
    const int CH = C / 4;
    int tid = blockIdx.x * 256 + threadIdx.x;
    int j = tid / CH, c4 = tid % CH;
    if (j >= K) return;
    int src = perm[j];
    float s = score[src];
    float4 v = ((const float4*)(xin + (size_t)src * C))[c4];
    v.x *= s; v.y *= s; v.z *= s; v.w *= s;
    ((float4*)(xpF + (size_t)j * C))[c4] = v;
    v4bf h, l;
    h[0] = (__bf16)v.x; l[0] = (__bf16)(v.x - (float)h[0]);
    h[1] = (__bf16)v.y; l[1] = (__bf16)(v.y - (float)h[1]);
    h[2] = (__bf16)v.z; l[2] = (__bf16)(v.z - (float)h[2]);
    h[3] = (__bf16)v.w; l[3] = (__bf16)(v.w - (float)h[3]);
    *(v4bf*)(xpHi + (size_t)j * C + c4 * 4) = h;
    *(v4bf*)(xpLo + (size_t)j * C + c4 * 4) = l;
}

// u[j] = base[j] + (mapping[j]>=0 ? deep[mapping[j]] : 0)  -> f32 + (hi,lo); uF may alias base
template<int C>
__global__ void unpool_add_kernel(const float* __restrict__ base, const float* __restrict__ deep,
                                  const int* __restrict__ mapping, float* __restrict__ uF,
                                  __bf16* __restrict__ uHi, __bf16* __restrict__ uLo, int M) {
    const int CH = C / 4;
    int tid = blockIdx.x * 256 + threadIdx.x;
    int j = tid / CH, c4 = tid % CH;
    if (j >= M) return;
    float4 v = ((const float4*)(base + (size_t)j * C))[c4];
    int m = mapping[j];
    if (m >= 0) {
        float4 d = ((const float4*)(deep + (size_t)m * C))[c4];
        v.x += d.x; v.y += d.y; v.z += d.z; v.w += d.w;
    }
    ((float4*)(uF + (size_t)j * C))[c4] = v;
    v4bf h, l;
    h[0] = (__bf16)v.x; l[0] = (__bf16)(v.x - (float)h[0]);
    h[1] = (__bf16)v.y; l[1] = (__bf16)(v.y - (float)h[1]);
    h[2] = (__bf16)v.z; l[2] = (__bf16)(v.z - (float)h[2]);
    h[3] = (__bf16)v.w; l[3] = (__bf16)(v.w - (float)h[3]);
    *(v4bf*)(uHi + (size_t)j * C + c4 * 4) = h;
    *(v4bf*)(uLo + (size_t)j * C + c4 * 4) = l;
}

__global__ void head_kernel(const float* __restrict__ x5, const float* __restrict__ lw,
                            const float* __restrict__ lb, void* __restrict__ out, int M,
                            const int* __restrict__ flag) {
    int row = blockIdx.x * 4 + (threadIdx.x >> 6);
    int lane = threadIdx.x & 63;
    if (row >= M) return;
    float a0 = x5[(size_t)row * 128 + lane];
    float a1 = x5[(size_t)row * 128 + 64 + lane];
    float d[NCLS];
#pragma unroll
    for (int o = 0; o < NCLS; ++o) {
        float p = a0 * lw[o * 128 + lane] + a1 * lw[o * 128 + 64 + lane];
#pragma unroll
        for (int off = 32; off >= 1; off >>= 1) p += __shfl_xor(p, off, 64);
        d[o] = p + lb[o];
    }
    float mx = d[0];
#pragma unroll
    for (int o = 1; o < NCLS; ++o) mx = fmaxf(mx, d[o]);
    float s = 0.f;
#pragma unroll
    for (int o = 0; o < NCLS; ++o) s += expf(d[o] - mx);
    float lse = mx + logf(s);
    if (lane < NCLS) {
        float v = d[0];
#pragma unroll
        for (int o = 1; o < NCLS; ++o) if (lane == o) v = d[o];
        float r = v - lse;
        if (*flag) ((float*)out)[(size_t)row * NCLS + lane] = r;
        else ((__hip_bfloat16*)out)[(size_t)row * NCLS + lane] = __float2bfloat16(r);
    }
}

extern "C" void kernel_launch(void* const* d_in, const int* in_sizes, int n_in,
                              void* d_out, int out_size, void* d_ws, size_t ws_size,
                              hipStream_t stream) {
    const void* x_raw   = d_in[0];
    const int*  ei      = (const int*)d_in[1];
    const void* w1_rel  = d_in[2];
    const void* w1_root = d_in[3];
    const void* b1      = d_in[4];
    const void* p1w     = d_in[5];
    const void* w2_rel  = d_in[6];
    const void* w2_root = d_in[7];
    const void* b2      = d_in[8];
    const void* p2w     = d_in[9];
    const void* w3_rel  = d_in[10];
    const void* w3_root = d_in[11];
    const void* b3      = d_in[12];
    const void* w4_rel  = d_in[13];
    const void* w4_root = d_in[14];
    const void* b4      = d_in[15];
    const void* w5_rel  = d_in[16];
    const void* w5_root = d_in[17];
    const void* b5      = d_in[18];
    const void* lw      = d_in[19];
    const void* lb      = d_in[20];

    char* base = (char*)d_ws;
    size_t off = 0;
    auto alloc = [&](size_t bytes) -> void* {
        void* p = base + off;
        off = (off + bytes + 255) & ~(size_t)255;
        return p;
    };
    int* flag = (int*)alloc(256);
    __bf16* w1rHi = (__bf16*)alloc(HID * FEAT * 2); __bf16* w1rLo = (__bf16*)alloc(HID * FEAT * 2);
    __bf16* w1tHi = (__bf16*)alloc(HID * FEAT * 2); __bf16* w1tLo = (__bf16*)alloc(HID * FEAT * 2);
    __bf16* w2rHi = (__bf16*)alloc(EMB * HID * 2);  __bf16* w2rLo = (__bf16*)alloc(EMB * HID * 2);
    __bf16* w2tHi = (__bf16*)alloc(EMB * HID * 2);  __bf16* w2tLo = (__bf16*)alloc(EMB * HID * 2);
    __bf16* w3rHi = (__bf16*)alloc(EMB * EMB * 2);  __bf16* w3rLo = (__bf16*)alloc(EMB * EMB * 2);
    __bf16* w3tHi = (__bf16*)alloc(EMB * EMB * 2);  __bf16* w3tLo = (__bf16*)alloc(EMB * EMB * 2);
    __bf16* w4rHi = (__bf16*)alloc(HID * EMB * 2);  __bf16* w4rLo = (__bf16*)alloc(HID * EMB * 2);
    __bf16* w4tHi = (__bf16*)alloc(HID * EMB * 2);  __bf16* w4tLo = (__bf16*)alloc(HID * EMB * 2);
    __bf16* w5rHi = (__bf16*)alloc(FEAT * HID * 2); __bf16* w5rLo = (__bf16*)alloc(FEAT * HID * 2);
    __bf16* w5tHi = (__bf16*)alloc(FEAT * HID * 2); __bf16* w5tLo = (__bf16*)alloc(FEAT * HID * 2);
    float* b1f = (float*)alloc(HID * 4);
    float* b2f = (float*)alloc(EMB * 4);
    float* b3f = (float*)alloc(EMB * 4);
    float* b4f = (float*)alloc(HID * 4);
    float* b5f = (float*)alloc(FEAT * 4);
    float* p1f = (float*)alloc(HID * 4);
    float* p2f = (float*)alloc(EMB * 4);
    float* lwf = (float*)alloc(NCLS * FEAT * 4);
    float* lbf = (float*)alloc(NCLS * 4);
    float* score = (float*)alloc((size_t)N0 * 4);
    unsigned long long* keys = (unsigned long long*)alloc((size_t)N0 * 8);
    int* rank  = (int*)alloc((size_t)N0 * 4);
    int* perm1 = (int*)alloc((size_t)K1 * 4);
    int* map1  = (int*)alloc((size_t)N0 * 4);
    int* perm2 = (int*)alloc((size_t)K2 * 4);
    int* map2  = (int*)alloc((size_t)K1 * 4);
    int* deg   = (int*)alloc((size_t)(N0 + 1) * 4);
    int* cursor= (int*)alloc((size_t)(N0 + 1) * 4);
    int* rp0   = (int*)alloc((size_t)(N0 + 1) * 4);
    int* rp1   = (int*)alloc((size_t)(K1 + 1) * 4);
    int* rp2   = (int*)alloc((size_t)(K2 + 1) * 4);
    int* cols0 = (int*)alloc((size_t)E0 * 4);
    int* cols1 = (int*)alloc((size_t)E0 * 4);
    int* cols2 = (int*)alloc((size_t)E0 * 4);
    // aliased activation arenas
    char*   arenaX  = (char*)alloc((size_t)N0 * 128 * 4);   // xf -> xp1f -> {xp2f,x3f} -> x4f -> x5f
    __bf16* arenaHi = (__bf16*)alloc((size_t)N0 * 128 * 2);
    __bf16* arenaLo = (__bf16*)alloc((size_t)N0 * 128 * 2);
    __bf16* aggHi   = (__bf16*)alloc((size_t)N0 * 128 * 2);
    __bf16* aggLo   = (__bf16*)alloc((size_t)N0 * 128 * 2);
    float*  x1f     = (float*)alloc((size_t)N0 * 128 * 4);  // persists; becomes u2 f32 in-place
    float*  x2f     = (float*)alloc((size_t)K1 * 64 * 4);   // persists; becomes u1 f32 in-place

    float* xf   = (float*)arenaX;
    float* xp1f = (float*)arenaX;
    float* xp2f = (float*)arenaX;
    float* x3f  = (float*)(arenaX + 8388608);
    float* x4f  = (float*)arenaX;
    float* x5f  = (float*)arenaX;
    __bf16 *xHi = arenaHi,  *xLo = arenaLo;
    __bf16 *xp1Hi = arenaHi, *xp1Lo = arenaLo;
    __bf16 *xp2Hi = arenaHi, *xp2Lo = arenaLo;
    __bf16 *u1Hi = arenaHi,  *u1Lo = arenaLo;
    __bf16 *u2Hi = arenaHi,  *u2Lo = arenaLo;
    float* u1f = x2f;

    const int* src0 = ei;
    const int* dst0 = ei + E0;

    auto g = [](long long n, int b) -> unsigned { return (unsigned)((n + b - 1) / b); };

    // ---- dtype detect + fused conversions ----
    detect_dtype_kernel<<<1, 256, 0, stream>>>((const unsigned*)x_raw, 4096, flag);
    x_convert_kernel<<<g((long long)N0 * FEAT, 256), 256, 0, stream>>>(x_raw, xf, xHi, xLo, N0 * FEAT, flag);
    {
        SplitJobs sj;
        sj.j[0] = {w1_rel,  w1rHi, w1rLo, HID * FEAT};
        sj.j[1] = {w1_root, w1tHi, w1tLo, HID * FEAT};
        sj.j[2] = {w2_rel,  w2rHi, w2rLo, EMB * HID};
        sj.j[3] = {w2_root, w2tHi, w2tLo, EMB * HID};
        sj.j[4] = {w3_rel,  w3rHi, w3rLo, EMB * EMB};
        sj.j[5] = {w3_root, w3tHi, w3tLo, EMB * EMB};
        sj.j[6] = {w4_rel,  w4rHi, w4rLo, HID * EMB};
        sj.j[7] = {w4_root, w4tHi, w4tLo, HID * EMB};
        sj.j[8] = {w5_rel,  w5rHi, w5rLo, FEAT * HID};
        sj.j[9] = {w5_root, w5tHi, w5tLo, FEAT * HID};
        dim3 grid(g(HID * FEAT, 256), 10);
        split_all_kernel<<<grid, 256, 0, stream>>>(sj, flag);
    }
    {
        F32Jobs fj;
        fj.j[0] = {b1, b1f, HID};
        fj.j[1] = {b2, b2f, EMB};
        fj.j[2] = {b3, b3f, EMB};
        fj.j[3] = {b4, b4f, HID};
        fj.j[4] = {b5, b5f, FEAT};
        fj.j[5] = {p1w, p1f, HID};
        fj.j[6] = {p2w, p2f, EMB};
        fj.j[7] = {lw, lwf, NCLS * FEAT};
        fj.j[8] = {lb, lbf, NCLS};
        f32_all_kernel<<<9, 256, 0, stream>>>(fj, flag);
    }

    // ---- CSR graph0 ----
    hipMemsetAsync(deg, 0, (size_t)N0 * 4, stream);
    deg_count_kernel<<<g(E0, 256), 256, 0, stream>>>(src0, dst0, E0, nullptr, nullptr, deg);
    exclusive_scan_kernel<<<1, 1024, 0, stream>>>(deg, rp0, cursor, N0);
    csr_fill_kernel<<<g(E0, 256), 256, 0, stream>>>(src0, dst0, E0, nullptr, nullptr, cursor, cols0);

    // ---- Layer 1 ----
    aggregate_kernel<128><<<g(N0, 8), 256, 0, stream>>>(rp0, cols0, xf, aggHi, aggLo, N0);
    linear_mfma_kernel<128, 128><<<g(N0, 64), 256, 0, stream>>>(N0, aggHi, aggLo, w1rHi, w1rLo,
                                                                xHi, xLo, w1tHi, w1tLo, b1f, x1f);

    // ---- Pool 1 ----
    score_kernel<128><<<g(N0, 4), 256, 0, stream>>>(x1f, p1f, N0, score);
    build_keys_kernel<<<g(N0, 256), 256, 0, stream>>>(score, keys, N0);
    hipMemsetAsync(rank, 0, (size_t)N0 * 4, stream);
    {
        dim3 grid(g(N0, 512), g(N0, RT));
        rank_count_kernel<<<grid, 256, 0, stream>>>(keys, N0, rank);
    }
    finalize_perm_kernel<<<g(N0, 256), 256, 0, stream>>>(rank, N0, K1, perm1, map1);
    pool_apply_kernel<128><<<g((long long)K1 * 32, 256), 256, 0, stream>>>(x1f, score, perm1, xp1f, xp1Hi, xp1Lo, K1);

    // ---- CSR graph1 ----
    hipMemsetAsync(deg, 0, (size_t)K1 * 4, stream);
    deg_count_kernel<<<g(E0, 256), 256, 0, stream>>>(src0, dst0, E0, map1, nullptr, deg);
    exclusive_scan_kernel<<<1, 1024, 0, stream>>>(deg, rp1, cursor, K1);
    csr_fill_kernel<<<g(E0, 256), 256, 0, stream>>>(src0, dst0, E0, map1, nullptr, cursor, cols1);

    // ---- Layer 2 ----
    aggregate_kernel<128><<<g(K1, 8), 256, 0, stream>>>(rp1, cols1, xp1f, aggHi, aggLo, K1);
    linear_mfma_kernel<128, 64><<<g(K1, 64), 256, 0, stream>>>(K1, aggHi, aggLo, w2rHi, w2rLo,
                                                               xp1Hi, xp1Lo, w2tHi, w2tLo, b2f, x2f);

    // ---- Pool 2 ----
    score_kernel<64><<<g(K1, 4), 256, 0, stream>>>(x2f, p2f, K1, score);
    build_keys_kernel<<<g(K1, 256), 256, 0, stream>>>(score, keys, K1);
    hipMemsetAsync(rank, 0, (size_t)K1 * 4, stream);
    {
        dim3 grid(g(K1, 512), g(K1, RT));
        rank_count_kernel<<<grid, 256, 0, stream>>>(keys, K1, rank);
    }
    finalize_perm_kernel<<<g(K1, 256), 256, 0, stream>>>(rank, K1, K2, perm2, map2);
    pool_apply_kernel<64><<<g((long long)K2 * 16, 256), 256, 0, stream>>>(x2f, score, perm2, xp2f, xp2Hi, xp2Lo, K2);

    // ---- CSR graph2 ----
    hipMemsetAsync(deg, 0, (size_t)K2 * 4, stream);
    deg_count_kernel<<<g(E0, 256), 256, 0, stream>>>(src0, dst0, E0, map1, map2, deg);
    exclusive_scan_kernel<<<1, 1024, 0, stream>>>(deg, rp2, cursor, K2);
    csr_fill_kernel<<<g(E0, 256), 256, 0, stream>>>(src0, dst0, E0, map1, map2, cursor, cols2);

    // ---- Layer 3 ----
    aggregate_kernel<64><<<g(K2, 16), 256, 0, stream>>>(rp2, cols2, xp2f, aggHi, aggLo, K2);
    linear_mfma_kernel<64, 64><<<g(K2, 64), 256, 0, stream>>>(K2, aggHi, aggLo, w3rHi, w3rLo,
                                                              xp2Hi, xp2Lo, w3tHi, w3tLo, b3f, x3f);

    // ---- Unpool 1 (in-place on x2f) ----
    unpool_add_kernel<64><<<g((long long)K1 * 16, 256), 256, 0, stream>>>(x2f, x3f, map2, u1f, u1Hi, u1Lo, K1);

    // ---- Layer 4 ----
    aggregate_kernel<64><<<g(K1, 16), 256, 0, stream>>>(rp1, cols1, u1f, aggHi, aggLo, K1);
    linear_mfma_kernel<64, 128><<<g(K1, 64), 256, 0, stream>>>(K1, aggHi, aggLo, w4rHi, w4rLo,
                                                               u1Hi, u1Lo, w4tHi, w4tLo, b4f, x4f);

    // ---- Unpool 2 (f32 in-place on x1f) ----
    unpool_add_kernel<128><<<g((long long)N0 * 32, 256), 256, 0, stream>>>(x1f, x4f, map1, x1f, u2Hi, u2Lo, N0);

    // ---- Layer 5 ----
    aggregate_kernel<128><<<g(N0, 8), 256, 0, stream>>>(rp0, cols0, x1f, aggHi, aggLo, N0);
    linear_mfma_kernel<128, 128><<<g(N0, 64), 256, 0, stream>>>(N0, aggHi, aggLo, w5rHi, w5rLo,
                                                                u2Hi, u2Lo, w5tHi, w5tLo, b5f, x5f);

    // ---- Head ----
    head_kernel<<<g(N0, 4), 256, 0, stream>>>(x5f, lwf, lbf, d_out, N0, flag);
}